// Round 19
// baseline (41.165 us; speedup 1.0000x reference)
//
#include <hip/hip_runtime.h>
#include <hip/hip_bf16.h>

#define BDIM 512

typedef __attribute__((ext_vector_type(8))) _Float16 f16x8;
typedef __attribute__((ext_vector_type(4))) _Float16 f16x4;
typedef __attribute__((ext_vector_type(4))) float f32x4;

// native v_exp_f32 computes 2^x; __exp2f doesn't exist in HIP
#define EXP2F(x) __builtin_amdgcn_exp2f(x)

// Local windowed attention with RoPE. b=32, n=4096, d=64, WINDOW=128, 1 backward window.
// R19: SINGLE-BARRIER PARALLEL-WINDOW structure. One block per window-pair; ALL THREE
// K/V halves staged up front into 3 LDS slots (109KB -> 1 block/CU); ONE __syncthreads;
// then waves 0-3 compute win0 and waves 4-7 compute win1 concurrently (each wave owns
// two 16-row m-tiles, no further barriers). Removes R18's two mid-kernel barriers and
// its exposed second stage phase; staging issues 3 halves' loads together (3x MLP).
// launch_bounds(512,2) -> VGPR cap 256: the chronic micro-spill pressure is gone.
// Occupancy drops to 8 waves/CU - R15/R16 falsified occupancy as the lever upward;
// this bets phase-count + load-queue depth matter more.
// Carried from R18 (32.5us best): swapped QK^T via mfma(K,Q) (per-query stats in
// c-layout, accO in row-layout, 1/s shuffled c->row at the end), permuted Vt columns
// (PV B-operand = one ds_read_b128), flat softmax over acc[16] (both halves resident),
// fused exp/pack/PV (s accumulated on the fly; PV needs only mx), exp2-domain scores
// (log2e folded into Q scale), tile-granular causal skips ((jt-8) <= mtIdx), diagonal
// mask 4g+r > c on tile 8+mtIdx. Spill sentinel: WRITE_SIZE == output 32.8MB.
__global__ __launch_bounds__(512, 2)
void la_kernel(const float* __restrict__ qg, const float* __restrict__ kg,
               const float* __restrict__ vg, float* __restrict__ outg)
{
    __shared__ _Float16 Ks[3][128][72];   // 55296 B
    __shared__ _Float16 Vt[3][64][140];   // 53760 B   total 109056 B -> 1 block/CU

    const int wp = blockIdx.x, bb = blockIdx.y;
    const int tid = threadIdx.x;
    const int w = tid >> 6, lane = tid & 63, g = lane >> 4, c = lane & 15;
    const int wi = w >> 2;                // window 0/1 handled by this wave
    const int ws = w & 3;                 // quarter within the window
    const int base = 256 * wp - 128;      // phys row of t=0 (block-common origin)
    const float NEG = -3.0e38f;
    const float NLT32 = -0.28782313662425572f;   // -ln(10000)/32
    const float QSCALE = 0.125f * 1.4426950408889634f;  // d^-0.5 * log2(e)
    const size_t rowb = (size_t)bb * 4096;

    // hoisted inverse frequencies
    const int cbK = (tid & 7) << 2;
    float invfK[4];
    #pragma unroll
    for (int u = 0; u < 4; ++u) invfK[u] = __expf((float)(cbK + u) * NLT32);
    float invfQ[8];
    #pragma unroll
    for (int u = 0; u < 8; ++u) invfQ[u] = __expf((float)(8 * g + u) * NLT32);

    const int jqV = tid >> 4, eqV = tid & 15;
    const int colbV = ((jqV & 24) << 2) + 8 * (jqV & 3) + 4 * ((jqV >> 2) & 1);

    // ---- Q raw loads for this wave's two m-tiles (issued first, consumed pre-sync) ----
    float4 qr[2][4];
    #pragma unroll
    for (int s = 0; s < 2; ++s) {
        const int tq = 128 * (wi + 1) + 32 * ws + 16 * s + c;
        const float* p = qg + (rowb + base + tq) * 64 + 8 * g;
        qr[s][0] = *(const float4*)p;
        qr[s][1] = *(const float4*)(p + 4);
        qr[s][2] = *(const float4*)(p + 32);
        qr[s][3] = *(const float4*)(p + 36);
    }

    // ---- stage physical half mm (t = 128*mm + j) into slot mm ----
    auto stage = [&](int mm) {
        #pragma unroll
        for (int it = 0; it < 2; ++it) {
            int j = (tid + it * 512) >> 3;         // 0..127
            int t = 128 * mm + j;
            const float* p = kg + (rowb + base + t) * 64 + cbK;
            float4 x1 = *(const float4*)p;
            float4 x2 = *(const float4*)(p + 32);
            const float* x1p = &x1.x;
            const float* x2p = &x2.x;
            f16x4 lo, hi;
            #pragma unroll
            for (int u = 0; u < 4; ++u) {
                float sn, cs; __sincosf((float)t * invfK[u], &sn, &cs);
                lo[u] = (_Float16)(x1p[u] * cs - x2p[u] * sn);
                hi[u] = (_Float16)(x2p[u] * cs + x1p[u] * sn);
            }
            *(f16x4*)&Ks[mm][j][cbK]      = lo;
            *(f16x4*)&Ks[mm][j][cbK + 32] = hi;
        }
        float4 x[4];
        #pragma unroll
        for (int v = 0; v < 4; ++v)
            x[v] = *(const float4*)(vg + (rowb + base + 128 * mm + 4 * jqV + v) * 64 + 4 * eqV);
        #pragma unroll
        for (int u = 0; u < 4; ++u) {
            f16x4 o;
            o[0] = (_Float16)((const float*)&x[0])[u];
            o[1] = (_Float16)((const float*)&x[1])[u];
            o[2] = (_Float16)((const float*)&x[2])[u];
            o[3] = (_Float16)((const float*)&x[3])[u];
            *(f16x4*)&Vt[mm][4 * eqV + u][colbV] = o;
        }
    };

    if (wp > 0) stage(0);                 // half 0 of block 0 is all padding
    stage(1);
    stage(2);

    // ---- RoPE Q into fragments (VALU only; overlaps staging load latency) ----
    f16x8 qa0[2], qa1[2];
    #pragma unroll
    for (int s = 0; s < 2; ++s) {
        const int tq = 128 * (wi + 1) + 32 * ws + 16 * s + c;
        float ra[8] = {qr[s][0].x,qr[s][0].y,qr[s][0].z,qr[s][0].w,
                       qr[s][1].x,qr[s][1].y,qr[s][1].z,qr[s][1].w};
        float rb[8] = {qr[s][2].x,qr[s][2].y,qr[s][2].z,qr[s][2].w,
                       qr[s][3].x,qr[s][3].y,qr[s][3].z,qr[s][3].w};
        #pragma unroll
        for (int u = 0; u < 8; ++u) {
            float sn, cs; __sincosf((float)tq * invfQ[u], &sn, &cs);
            float a = ra[u] * QSCALE, b = rb[u] * QSCALE;
            qa0[s][u] = (_Float16)(a * cs - b * sn);
            qa1[s][u] = (_Float16)(b * cs + a * sn);
        }
    }

    __syncthreads();                      // the ONLY barrier

    // ---- compute one m-tile (window wi, m-tile mtIdx in [0,8)) ----
    // jt 0..7  -> half wi   (slot wi),   no causal mask
    // jt 8..15 -> half wi+1 (slot wi+1), causal; computed iff jt-8 <= mtIdx;
    //             diagonal tile jt == 8+mtIdx partially masked where 4g+r > c
    auto computeM = [&](int mtIdx, f16x8 qa, f16x8 qb) {
        const bool skipFirst = (wp == 0 && wi == 0);
        const int sl0 = wi, sl1 = wi + 1;
        const f32x4 CZERO = (f32x4){0.f, 0.f, 0.f, 0.f};

        f32x4 acc[16];
        #pragma unroll
        for (int jt = 0; jt < 16; ++jt) {
            const bool doit = (jt < 8) ? (!skipFirst) : ((jt - 8) <= mtIdx);
            if (doit) {
                const int sl = (jt < 8) ? sl0 : sl1;
                const int row = (jt & 7) * 16 + c;
                f16x8 kb0 = *(const f16x8*)&Ks[sl][row][8 * g];
                f16x8 kb1 = *(const f16x8*)&Ks[sl][row][32 + 8 * g];
                acc[jt] = __builtin_amdgcn_mfma_f32_16x16x32_f16(kb0, qa, CZERO, 0, 0, 0);
                acc[jt] = __builtin_amdgcn_mfma_f32_16x16x32_f16(kb1, qb, acc[jt], 0, 0, 0);
            }
        }

        // mask (diag tile only) + max over computed tiles
        float mx = NEG;
        #pragma unroll
        for (int jt = 0; jt < 16; ++jt) {
            const bool doit = (jt < 8) ? (!skipFirst) : ((jt - 8) <= mtIdx);
            if (doit) {
                if (jt >= 8 && (jt - 8) == mtIdx) {
                    #pragma unroll
                    for (int r = 0; r < 4; ++r)
                        if (4 * g + r > c) acc[jt][r] = NEG;
                }
                #pragma unroll
                for (int r = 0; r < 4; ++r) mx = fmaxf(mx, acc[jt][r]);
            }
        }
        mx = fmaxf(mx, __shfl_xor(mx, 16));
        mx = fmaxf(mx, __shfl_xor(mx, 32));

        // fused: per 32-key group, exp2 + pack ONE fragment + 4 PV MFMAs; s on the fly
        f32x4 accO[4];
        #pragma unroll
        for (int nt = 0; nt < 4; ++nt) accO[nt] = CZERO;

        float s = 0.f;
        #pragma unroll
        for (int st = 0; st < 8; ++st) {
            const bool grp = (st < 4) ? (!skipFirst) : ((2 * st - 8) <= mtIdx);
            if (grp) {
                f16x8 pa;
                #pragma unroll
                for (int r = 0; r < 4; ++r) {
                    float p = EXP2F(acc[2 * st][r] - mx);     // masked -> 0
                    s += p;
                    pa[r] = (_Float16)p;
                }
                const bool oddOk = (st < 4) || ((2 * st - 7) <= mtIdx);
                if (oddOk) {
                    #pragma unroll
                    for (int r = 0; r < 4; ++r) {
                        float p = EXP2F(acc[2 * st + 1][r] - mx);
                        s += p;
                        pa[4 + r] = (_Float16)p;
                    }
                } else {
                    #pragma unroll
                    for (int r = 0; r < 4; ++r) pa[4 + r] = (_Float16)0.f;
                }
                const int sl = (st < 4) ? sl0 : sl1;
                #pragma unroll
                for (int nt = 0; nt < 4; ++nt) {
                    f16x8 vb = *(const f16x8*)&Vt[sl][nt * 16 + c][(st & 3) * 32 + 8 * g];
                    accO[nt] = __builtin_amdgcn_mfma_f32_16x16x32_f16(pa, vb, accO[nt], 0, 0, 0);
                }
            }
        }
        s += __shfl_xor(s, 16);
        s += __shfl_xor(s, 32);

        // epilogue: 1/s (c-layout) -> row-layout, store
        float rcp = 1.0f / s;
        float rcpD[4];
        #pragma unroll
        for (int r = 0; r < 4; ++r)
            rcpD[r] = __shfl(rcp, (lane & 48) | (4 * g + r));

        float* op = outg + (rowb + base + 128 * (wi + 1) + 16 * mtIdx) * 64;
        #pragma unroll
        for (int nt = 0; nt < 4; ++nt)
            #pragma unroll
            for (int r = 0; r < 4; ++r)
                op[(size_t)(4 * g + r) * 64 + nt * 16 + c] = accO[nt][r] * rcpD[r];
    };

    computeM(2 * ws,     qa0[0], qa1[0]);
    computeM(2 * ws + 1, qa0[1], qa1[1]);
}

extern "C" void kernel_launch(void* const* d_in, const int* in_sizes, int n_in,
                              void* d_out, int out_size, void* d_ws, size_t ws_size,
                              hipStream_t stream) {
    (void)in_sizes; (void)n_in; (void)out_size; (void)d_ws; (void)ws_size;
    const float* q = (const float*)d_in[0];
    const float* k = (const float*)d_in[1];
    const float* v = (const float*)d_in[2];
    float* out = (float*)d_out;
    dim3 grid(16, 32);  // x = window-pair, y = batch
    la_kernel<<<grid, BDIM, 0, stream>>>(q, k, v, out);
}

// Round 20
// 31.922 us; speedup vs baseline: 1.2895x; 1.2895x over previous
//
#include <hip/hip_runtime.h>
#include <hip/hip_bf16.h>

#define BDIM 512

typedef __attribute__((ext_vector_type(8))) _Float16 f16x8;
typedef __attribute__((ext_vector_type(4))) _Float16 f16x4;
typedef __attribute__((ext_vector_type(4))) float f32x4;

// native v_exp_f32 computes 2^x; __exp2f doesn't exist in HIP
#define EXP2F(x) __builtin_amdgcn_exp2f(x)

// Local windowed attention with RoPE. b=32, n=4096, d=64, WINDOW=128, 1 backward window.
// ONE BLOCK PER WINDOW-PAIR (RoPE relative-position invariance -> middle K/V half
// shared; block-common origin, t in [0,384)). 3 halves in 2 rolling LDS slots
// (72.7KB, 2 blocks/CU, launch_bounds(512,4); occupancy axis falsified R15/R16/R19).
// R20 = R18 + FRONT-STAGING LOAD/CONVERT SPLIT: all 20 float4 global loads (Q, K0,
// V0, K1, V1) are issued before any convert -> 2x in-flight loads during the start
// phase. Little's-law arithmetic: kernel moves 97.7MB at 3.0TB/s (48% achievable);
// staging-phase MLP is the limiter, not occupancy. Payload (80 VGPR) dies before
// any MFMA, so R3/R14's hold-across-compute spill mode doesn't apply.
// stage(2) stays fused (R14: splitting it cost ~1us).
// Carried from R18 (32.5us): swapped QK^T via mfma(K,Q) (stats c-layout, accO
// row-layout, 1/s shuffled c->row), permuted Vt columns (PV B = one ds_read_b128),
// flat softmax over acc[16], fused exp/pack/PV, exp2-domain scores, tile-granular
// causal skips, diag mask 4g+r > c. Spill sentinel: WRITE_SIZE == output 32.8MB.
__global__ __launch_bounds__(512, 4)
void la_kernel(const float* __restrict__ qg, const float* __restrict__ kg,
               const float* __restrict__ vg, float* __restrict__ outg)
{
    __shared__ _Float16 Ks[2][128][72];   // 36864 B
    __shared__ _Float16 Vt[2][64][140];   // 35840 B   total 72704 B

    const int wp = blockIdx.x, bb = blockIdx.y;
    const int tid = threadIdx.x;
    const int wv = tid >> 6, lane = tid & 63, g = lane >> 4, c = lane & 15;
    const int base = 256 * wp - 128;      // phys row of t=0 (block-common origin)
    const float NEG = -3.0e38f;
    const float NLT32 = -0.28782313662425572f;   // -ln(10000)/32
    const float QSCALE = 0.125f * 1.4426950408889634f;  // d^-0.5 * log2(e)
    const size_t rowb = (size_t)bb * 4096;

    // hoisted inverse frequencies
    const int cbK = (tid & 7) << 2;
    float invfK[4];
    #pragma unroll
    for (int u = 0; u < 4; ++u) invfK[u] = __expf((float)(cbK + u) * NLT32);
    float invfQ[8];
    #pragma unroll
    for (int u = 0; u < 8; ++u) invfQ[u] = __expf((float)(8 * g + u) * NLT32);

    const int jqV = tid >> 4, eqV = tid & 15;
    const int colbV = ((jqV & 24) << 2) + 8 * (jqV & 3) + 4 * ((jqV >> 2) & 1);

    const int qrow = wv * 16 + c;

    // ---- staging split: raw loads / convert+LDS-write ----
    auto stageLoad = [&](int mm, float4* kx, float4* vx) {
        #pragma unroll
        for (int it = 0; it < 2; ++it) {
            int j = (tid + it * 512) >> 3;         // 0..127
            const float* p = kg + (rowb + base + 128 * mm + j) * 64 + cbK;
            kx[2 * it]     = *(const float4*)p;
            kx[2 * it + 1] = *(const float4*)(p + 32);
        }
        #pragma unroll
        for (int w = 0; w < 4; ++w)
            vx[w] = *(const float4*)(vg + (rowb + base + 128 * mm + 4 * jqV + w) * 64 + 4 * eqV);
    };
    auto stageConv = [&](int mm, const float4* kx, const float4* vx) {
        const int sl = mm & 1;
        #pragma unroll
        for (int it = 0; it < 2; ++it) {
            int j = (tid + it * 512) >> 3;
            int t = 128 * mm + j;
            const float* x1p = (const float*)&kx[2 * it];
            const float* x2p = (const float*)&kx[2 * it + 1];
            f16x4 lo, hi;
            #pragma unroll
            for (int u = 0; u < 4; ++u) {
                float sn, cs; __sincosf((float)t * invfK[u], &sn, &cs);
                lo[u] = (_Float16)(x1p[u] * cs - x2p[u] * sn);
                hi[u] = (_Float16)(x2p[u] * cs + x1p[u] * sn);
            }
            *(f16x4*)&Ks[sl][j][cbK]      = lo;
            *(f16x4*)&Ks[sl][j][cbK + 32] = hi;
        }
        #pragma unroll
        for (int u = 0; u < 4; ++u) {
            f16x4 o;
            o[0] = (_Float16)((const float*)&vx[0])[u];
            o[1] = (_Float16)((const float*)&vx[1])[u];
            o[2] = (_Float16)((const float*)&vx[2])[u];
            o[3] = (_Float16)((const float*)&vx[3])[u];
            *(f16x4*)&Vt[sl][4 * eqV + u][colbV] = o;
        }
    };
    auto stageFused = [&](int mm) {       // for stage(2): load+convert in one pass
        float4 kx[4], vx[4];
        stageLoad(mm, kx, vx);
        stageConv(mm, kx, vx);
    };

    // ---- Q: split load / RoPE ----
    auto loadQraw = [&](int wi, float4* qr) {
        const int tq = 128 * (wi + 1) + qrow;
        const float* p = qg + (rowb + base + tq) * 64 + 8 * g;
        qr[0] = *(const float4*)p;
        qr[1] = *(const float4*)(p + 4);
        qr[2] = *(const float4*)(p + 32);
        qr[3] = *(const float4*)(p + 36);
    };
    auto ropeQ = [&](int wi, const float4* qr, f16x8& qa0, f16x8& qa1) {
        const int tq = 128 * (wi + 1) + qrow;
        float ra[8] = {qr[0].x,qr[0].y,qr[0].z,qr[0].w,qr[1].x,qr[1].y,qr[1].z,qr[1].w};
        float rb[8] = {qr[2].x,qr[2].y,qr[2].z,qr[2].w,qr[3].x,qr[3].y,qr[3].z,qr[3].w};
        #pragma unroll
        for (int u = 0; u < 8; ++u) {
            float sn, cs; __sincosf((float)tq * invfQ[u], &sn, &cs);
            float a = ra[u] * QSCALE, b = rb[u] * QSCALE;
            qa0[u] = (_Float16)(a * cs - b * sn);
            qa1[u] = (_Float16)(b * cs + a * sn);
        }
    };

    // ---- compute one window (wi), flat softmax, fused exp+pack+PV ----
    auto computeWin = [&](int wi, f16x8 qa0, f16x8 qa1) {
        const bool skipFirst = (wp == 0 && wi == 0);  // padding half
        const int sl0 = wi & 1, sl1 = (wi + 1) & 1;
        const f32x4 CZERO = (f32x4){0.f, 0.f, 0.f, 0.f};

        f32x4 acc[16];
        #pragma unroll
        for (int jt = 0; jt < 16; ++jt) {
            const bool doit = (jt < 8) ? (!skipFirst) : ((jt - 8) <= wv);
            if (doit) {
                const int sl = (jt < 8) ? sl0 : sl1;
                const int row = (jt & 7) * 16 + c;
                f16x8 kb0 = *(const f16x8*)&Ks[sl][row][8 * g];
                f16x8 kb1 = *(const f16x8*)&Ks[sl][row][32 + 8 * g];
                acc[jt] = __builtin_amdgcn_mfma_f32_16x16x32_f16(kb0, qa0, CZERO, 0, 0, 0);
                acc[jt] = __builtin_amdgcn_mfma_f32_16x16x32_f16(kb1, qa1, acc[jt], 0, 0, 0);
            }
        }

        // mask (diag tile only) + max over computed tiles
        float mx = NEG;
        #pragma unroll
        for (int jt = 0; jt < 16; ++jt) {
            const bool doit = (jt < 8) ? (!skipFirst) : ((jt - 8) <= wv);
            if (doit) {
                if (jt >= 8 && jt == 8 + wv) {
                    #pragma unroll
                    for (int r = 0; r < 4; ++r)
                        if (4 * g + r > c) acc[jt][r] = NEG;
                }
                #pragma unroll
                for (int r = 0; r < 4; ++r) mx = fmaxf(mx, acc[jt][r]);
            }
        }
        mx = fmaxf(mx, __shfl_xor(mx, 16));
        mx = fmaxf(mx, __shfl_xor(mx, 32));

        // fused: per 32-key group, exp2 + pack ONE fragment + 4 PV MFMAs; s on the fly
        f32x4 accO[4];
        #pragma unroll
        for (int nt = 0; nt < 4; ++nt) accO[nt] = CZERO;

        float s = 0.f;
        #pragma unroll
        for (int st = 0; st < 8; ++st) {
            const bool grp = (st < 4) ? (!skipFirst) : ((2 * st - 8) <= wv);
            if (grp) {
                f16x8 pa;
                #pragma unroll
                for (int r = 0; r < 4; ++r) {
                    float p = EXP2F(acc[2 * st][r] - mx);     // masked -> 0
                    s += p;
                    pa[r] = (_Float16)p;
                }
                const bool oddOk = (st < 4) || ((2 * st - 7) <= wv);
                if (oddOk) {
                    #pragma unroll
                    for (int r = 0; r < 4; ++r) {
                        float p = EXP2F(acc[2 * st + 1][r] - mx);
                        s += p;
                        pa[4 + r] = (_Float16)p;
                    }
                } else {
                    #pragma unroll
                    for (int r = 0; r < 4; ++r) pa[4 + r] = (_Float16)0.f;
                }
                const int sl = (st < 4) ? sl0 : sl1;
                #pragma unroll
                for (int nt = 0; nt < 4; ++nt) {
                    f16x8 vb = *(const f16x8*)&Vt[sl][nt * 16 + c][(st & 3) * 32 + 8 * g];
                    accO[nt] = __builtin_amdgcn_mfma_f32_16x16x32_f16(pa, vb, accO[nt], 0, 0, 0);
                }
            }
        }
        s += __shfl_xor(s, 16);
        s += __shfl_xor(s, 32);

        // epilogue: 1/s (c-layout) -> row-layout, store
        float rcp = 1.0f / s;
        float rcpD[4];
        #pragma unroll
        for (int r = 0; r < 4; ++r)
            rcpD[r] = __shfl(rcp, (lane & 48) | (4 * g + r));

        float* op = outg + (rowb + base + 128 * (wi + 1) + wv * 16) * 64;
        #pragma unroll
        for (int nt = 0; nt < 4; ++nt)
            #pragma unroll
            for (int r = 0; r < 4; ++r)
                op[(size_t)(4 * g + r) * 64 + nt * 16 + c] = accO[nt][r] * rcpD[r];
    };

    // ---- schedule: issue ALL front loads (Q, K0, V0, K1, V1) -> convert both ->
    //      ropeQ(0) -> sync -> win0 -> Qraw(1) -> sync -> stage(2) fused ->
    //      ropeQ(1) -> sync -> win1 ----
    float4 qr[4];
    loadQraw(0, qr);
    float4 k0[4], v0[4], k1[4], v1[4];
    if (wp > 0) stageLoad(0, k0, v0);
    stageLoad(1, k1, v1);
    if (wp > 0) stageConv(0, k0, v0);
    stageConv(1, k1, v1);

    f16x8 qA, qB;
    ropeQ(0, qr, qA, qB);
    __syncthreads();
    computeWin(0, qA, qB);
    loadQraw(1, qr);                      // issue win1's Q before the barrier
    __syncthreads();                      // all reads of slot0 done
    stageFused(2);
    ropeQ(1, qr, qA, qB);
    __syncthreads();
    computeWin(1, qA, qB);
}

extern "C" void kernel_launch(void* const* d_in, const int* in_sizes, int n_in,
                              void* d_out, int out_size, void* d_ws, size_t ws_size,
                              hipStream_t stream) {
    (void)in_sizes; (void)n_in; (void)out_size; (void)d_ws; (void)ws_size;
    const float* q = (const float*)d_in[0];
    const float* k = (const float*)d_in[1];
    const float* v = (const float*)d_in[2];
    float* out = (float*)d_out;
    dim3 grid(16, 32);  // x = window-pair, y = batch
    la_kernel<<<grid, BDIM, 0, stream>>>(q, k, v, out);
}